// Round 17
// baseline (120.063 us; speedup 1.0000x reference)
//
#include <hip/hip_runtime.h>

#define LB __launch_bounds__(256)

typedef __bf16 bf16x8 __attribute__((ext_vector_type(8)));
typedef float f32x4 __attribute__((ext_vector_type(4)));
typedef float f32x16 __attribute__((ext_vector_type(16)));
typedef unsigned int u32;
typedef unsigned int u32x2 __attribute__((ext_vector_type(2)));

constexpr int B = 2, S = 2048, D = 1024, H = 16, DK = 64;
constexpr int M = B * S;   // 4096 tokens
constexpr int K = D;       // 1024 inner dim for projections

__device__ __forceinline__ unsigned short f2bf(float f) {
    union { float f; unsigned u; } v; v.f = f;
    unsigned r = v.u + 0x7fffu + ((v.u >> 16) & 1u);
    return (unsigned short)(r >> 16);
}

__device__ __forceinline__ u32 pk2bf(float lo, float hi) {
    union { __bf16 h[2]; u32 w; } u;
    u.h[0] = (__bf16)lo; u.h[1] = (__bf16)hi;
    return u.w;
}

__device__ __forceinline__ float bf2f(unsigned short h) {
    union { unsigned u; float f; } v; v.u = ((unsigned)h) << 16;
    return v.f;
}

__device__ __forceinline__ void gld_lds16(const unsigned short* g, unsigned short* l) {
    __builtin_amdgcn_global_load_lds(
        (const __attribute__((address_space(1))) unsigned int*)g,
        (__attribute__((address_space(3))) unsigned int*)l, 16, 0, 0);
}

// ---- fused fp32 -> bf16 convert of x|wq|wk|wv|wo into contiguous ws ----
__global__ LB void cvt_all(const float* __restrict__ x,  const float* __restrict__ wq,
                           const float* __restrict__ wk, const float* __restrict__ wv,
                           const float* __restrict__ wo, unsigned short* __restrict__ dst) {
    const size_t NX = (size_t)M * D;          // 4M
    const size_t NW = (size_t)D * D;          // 1M
    size_t i = ((size_t)blockIdx.x * 256 + threadIdx.x) * 4;
    if (i >= NX + 4 * NW) return;
    const float* src; size_t off;
    if      (i < NX)          { src = x;  off = i; }
    else if (i < NX + NW)     { src = wq; off = i - NX; }
    else if (i < NX + 2 * NW) { src = wk; off = i - NX - NW; }
    else if (i < NX + 3 * NW) { src = wv; off = i - NX - 2 * NW; }
    else                      { src = wo; off = i - NX - 3 * NW; }
    float4 f = *reinterpret_cast<const float4*>(src + off);
    ushort4 o;
    o.x = f2bf(f.x); o.y = f2bf(f.y); o.z = f2bf(f.z); o.w = f2bf(f.w);
    *reinterpret_cast<ushort4*>(dst + i) = o;
}

// ---- fused QKV projection (R15/R16-verified: scatter epilogue + XCD swizzle) ----
__global__ LB void gemm_qkv(const unsigned short* __restrict__ A,
                            const unsigned short* __restrict__ wqb,
                            const unsigned short* __restrict__ wkb,
                            const unsigned short* __restrict__ wvb,
                            unsigned short* __restrict__ qo,
                            unsigned short* __restrict__ ko,
                            unsigned short* __restrict__ vo) {
    __shared__ __align__(16) unsigned short lA[128 * 32];
    __shared__ __align__(16) unsigned short lB[128 * 32];
    const int z = blockIdx.y;
    const unsigned short* W = (z == 0) ? wqb : ((z == 1) ? wkb : wvb);
    int bid = blockIdx.x;
    int m0 = (((bid >> 6) << 3) | (bid & 7)) * 128;   // XCD-grouped m-tile
    int n0 = ((bid >> 3) & 7) * 128;
    int t = threadIdx.x;
    int w = t >> 6, lane = t & 63;
    int r = lane & 15, g = lane >> 4;
    int wr = w >> 1, wc = w & 1;
    int rowT = t >> 2, colOff = (t & 3) * 8;

    f32x4 acc[4][4];
#pragma unroll
    for (int mi = 0; mi < 4; ++mi)
#pragma unroll
        for (int ni = 0; ni < 4; ++ni) acc[mi][ni] = f32x4{0.f, 0.f, 0.f, 0.f};

    for (int k0 = 0; k0 < K; k0 += 32) {
        gld_lds16(A + (size_t)(m0 + rowT) * K + k0 + colOff,      lA + (w * 64) * 8);
        gld_lds16(A + (size_t)(m0 + 64 + rowT) * K + k0 + colOff, lA + (256 + w * 64) * 8);
        gld_lds16(W + (size_t)(n0 + rowT) * K + k0 + colOff,      lB + (w * 64) * 8);
        gld_lds16(W + (size_t)(n0 + 64 + rowT) * K + k0 + colOff, lB + (256 + w * 64) * 8);
        __syncthreads();
        bf16x8 af[4], bfr[4];
#pragma unroll
        for (int mi = 0; mi < 4; ++mi)
            af[mi] = *reinterpret_cast<const bf16x8*>(&lA[(wr * 64 + mi * 16 + r) * 32 + g * 8]);
#pragma unroll
        for (int ni = 0; ni < 4; ++ni)
            bfr[ni] = *reinterpret_cast<const bf16x8*>(&lB[(wc * 64 + ni * 16 + r) * 32 + g * 8]);
#pragma unroll
        for (int mi = 0; mi < 4; ++mi)
#pragma unroll
            for (int ni = 0; ni < 4; ++ni)
                acc[mi][ni] = __builtin_amdgcn_mfma_f32_16x16x32_bf16(af[mi], bfr[ni], acc[mi][ni], 0, 0, 0);
        __syncthreads();
    }

    const float QSCALE = 0.125f * 1.44269504088896341f;
    float scale = (z == 0) ? QSCALE : 1.0f;
    unsigned short* dst = (z == 0) ? qo : ((z == 1) ? ko : vo);
#pragma unroll
    for (int mi = 0; mi < 4; ++mi)
#pragma unroll
        for (int ni = 0; ni < 4; ++ni)
#pragma unroll
            for (int j = 0; j < 4; ++j) {
                int row = m0 + wr * 64 + mi * 16 + g * 4 + j;
                int col = n0 + wc * 64 + ni * 16 + r;
                int b = row >> 11, s = row & (S - 1);
                int h = col >> 6, dk = col & 63;
                size_t bh = (size_t)(b * H + h);
                unsigned short val = f2bf(acc[mi][ni][j] * scale);
                if (z == 0) {
                    dst[(bh * S + s) * DK + dk] = val;
                } else if (z == 1) {
                    int kt32 = s >> 5, q5k = s & 31;
                    int dsi = dk >> 4, hlk = (dk >> 3) & 1, e = dk & 7;
                    dst[(((bh * 64 + kt32) * 4 + dsi) * 64 + (hlk * 32 + q5k)) * 8 + e] = val;
                } else {
                    int ktile = s >> 6, ks2 = (s >> 4) & 3, hlv = (s >> 3) & 1, e = s & 7;
                    int rh = dk >> 5, q5r = dk & 31;
                    dst[(((bh * 32 + ktile) * 8 + rh * 4 + ks2) * 64 + (hlv * 32 + q5r)) * 8 + e] = val;
                }
            }
}

// ---- output projection: 128x64 tiles, 512 blocks (2 blocks/CU), XCD-grouped ----
__global__ LB void out_gemm(const unsigned short* __restrict__ A,
                            const unsigned short* __restrict__ W,
                            float* __restrict__ out) {
    __shared__ __align__(16) unsigned short lA[128 * 32];
    __shared__ __align__(16) unsigned short lB[64 * 32];
    int bid = blockIdx.x;                              // 512
    int m0 = (((bid >> 7) << 3) | (bid & 7)) * 128;    // m-tile 0..31, XCD-grouped
    int n0 = ((bid >> 3) & 15) * 64;                   // n-tile 0..15
    int t = threadIdx.x;
    int w = t >> 6, lane = t & 63;
    int r = lane & 15, g = lane >> 4;
    int wr = w >> 1, wc = w & 1;                       // 2m x 2n waves; wave = 64x32
    int rowT = t >> 2, colOff = (t & 3) * 8;

    f32x4 acc[4][2];
#pragma unroll
    for (int mi = 0; mi < 4; ++mi)
#pragma unroll
        for (int ni = 0; ni < 2; ++ni) acc[mi][ni] = f32x4{0.f, 0.f, 0.f, 0.f};

    for (int k0 = 0; k0 < K; k0 += 32) {
        gld_lds16(A + (size_t)(m0 + rowT) * K + k0 + colOff,      lA + (w * 64) * 8);
        gld_lds16(A + (size_t)(m0 + 64 + rowT) * K + k0 + colOff, lA + (256 + w * 64) * 8);
        gld_lds16(W + (size_t)(n0 + rowT) * K + k0 + colOff,      lB + (w * 64) * 8);
        __syncthreads();
        bf16x8 af[4], bfr[2];
#pragma unroll
        for (int mi = 0; mi < 4; ++mi)
            af[mi] = *reinterpret_cast<const bf16x8*>(&lA[(wr * 64 + mi * 16 + r) * 32 + g * 8]);
#pragma unroll
        for (int ni = 0; ni < 2; ++ni)
            bfr[ni] = *reinterpret_cast<const bf16x8*>(&lB[(wc * 32 + ni * 16 + r) * 32 + g * 8]);
#pragma unroll
        for (int mi = 0; mi < 4; ++mi)
#pragma unroll
            for (int ni = 0; ni < 2; ++ni)
                acc[mi][ni] = __builtin_amdgcn_mfma_f32_16x16x32_bf16(af[mi], bfr[ni], acc[mi][ni], 0, 0, 0);
        __syncthreads();
    }

#pragma unroll
    for (int mi = 0; mi < 4; ++mi)
#pragma unroll
        for (int ni = 0; ni < 2; ++ni)
#pragma unroll
            for (int j = 0; j < 4; ++j) {
                int row = m0 + wr * 64 + mi * 16 + g * 4 + j;
                int col = n0 + wc * 32 + ni * 16 + r;
                out[(size_t)row * D + col] = acc[mi][ni][j];
            }
}

// ---- causal flash attention, kv-split: 4096 single-wave jobs (bh, qt, half),
// each covers kv-tiles [n_lo, n_hi) of its q-tile; writes UNNORMALIZED partial
// O (bf16) + partial row-sum l (f32). Body = R16-verified (permlane PF, static
// softmax, ones-MFMA row-sum, K+V reg dbuf, frag-major coalesced loads).
__global__ __launch_bounds__(64) void flash_attn(
        const unsigned short* __restrict__ q,
        const unsigned short* __restrict__ kmat,
        const unsigned short* __restrict__ vt,
        unsigned short* __restrict__ p0,
        unsigned short* __restrict__ p1,
        float* __restrict__ l0,
        float* __restrict__ l1) {
    int bid = blockIdx.x;                 // 4096
    int qt = 63 - (bid >> 6);             // LPT: longest jobs first
    int half = (bid >> 5) & 1;
    int bh = bid & 31;
    int b = bh >> 4, hd = bh & 15;
    int q0 = qt << 5;
    int nt = (qt + 2) >> 1;               // kv-tiles of 64
    int nh1 = (nt + 1) >> 1;
    int n_lo = half ? nh1 : 0;
    int n_hi = half ? nt : nh1;

    unsigned short* Pd = half ? p1 : p0;
    float* Ld = half ? l1 : l0;

    int l = threadIdx.x;
    int q5 = l & 31, hl = l >> 5;
    int qglob = q0 + q5;

    const unsigned short* qp = q    + (size_t)bh * S * DK;
    const unsigned short* kf = kmat + (size_t)bh * S * DK;   // fragment-major
    const unsigned short* vf = vt   + (size_t)bh * S * DK;   // fragment-major

    bf16x8 ones;
#pragma unroll
    for (int i = 0; i < 8; ++i) ones[i] = (__bf16)1.0f;

    const f32x16 z16 = {0,0,0,0,0,0,0,0,0,0,0,0,0,0,0,0};

    bf16x8 qf[4];
#pragma unroll
    for (int dsi = 0; dsi < 4; ++dsi)
        qf[dsi] = *reinterpret_cast<const bf16x8*>(qp + (size_t)qglob * DK + dsi * 16 + hl * 8);

    f32x16 acc0 = z16, acc1 = z16, accl = z16;

    auto loadK = [&](bf16x8 (&kr)[8], int kb) {
        const unsigned short* base = kf + (size_t)(kb >> 5) * 4 * 512 + l * 8;
#pragma unroll
        for (int dsi = 0; dsi < 4; ++dsi) {
            kr[dsi]     = *reinterpret_cast<const bf16x8*>(base + dsi * 512);
            kr[4 + dsi] = *reinterpret_cast<const bf16x8*>(base + (4 + dsi) * 512);
        }
    };
    auto loadV = [&](bf16x8 (&vr)[8], int kb) {
        const unsigned short* base = vf + (size_t)(kb >> 6) * 8 * 512 + l * 8;
#pragma unroll
        for (int i2 = 0; i2 < 8; ++i2)
            vr[i2] = *reinterpret_cast<const bf16x8*>(base + i2 * 512);
    };
    auto compute = [&](bf16x8 (&kr)[8], bf16x8 (&vr)[8], int kb) {
        f32x16 st0 = __builtin_amdgcn_mfma_f32_32x32x16_bf16(kr[0], qf[0], z16, 0, 0, 0);
        f32x16 st1 = __builtin_amdgcn_mfma_f32_32x32x16_bf16(kr[4], qf[0], z16, 0, 0, 0);
#pragma unroll
        for (int dsi = 1; dsi < 4; ++dsi) {
            st0 = __builtin_amdgcn_mfma_f32_32x32x16_bf16(kr[dsi],     qf[dsi], st0, 0, 0, 0);
            st1 = __builtin_amdgcn_mfma_f32_32x32x16_bf16(kr[4 + dsi], qf[dsi], st1, 0, 0, 0);
        }
        if (kb + 31 > q0) {
#pragma unroll
            for (int r = 0; r < 16; ++r) {
                int kv = kb + (r & 3) + 8 * (r >> 2) + 4 * hl;
                st0[r] = (kv <= qglob) ? st0[r] : -1e30f;
            }
        }
        if (kb + 63 > q0) {
#pragma unroll
            for (int r = 0; r < 16; ++r) {
                int kv = kb + 32 + (r & 3) + 8 * (r >> 2) + 4 * hl;
                st1[r] = (kv <= qglob) ? st1[r] : -1e30f;
            }
        }
        // static softmax: p = exp2(s); masked -> exp2(-1e30) = 0
#pragma unroll
        for (int r = 0; r < 16; ++r) { st0[r] = exp2f(st0[r]); st1[r] = exp2f(st1[r]); }
        // pack to bf16; PF build via permlane32_swap (R16-verified)
        u32 pk[2][8];
#pragma unroll
        for (int rg = 0; rg < 4; ++rg) {
            pk[0][2*rg]   = pk2bf(st0[4*rg],   st0[4*rg+1]);
            pk[0][2*rg+1] = pk2bf(st0[4*rg+2], st0[4*rg+3]);
            pk[1][2*rg]   = pk2bf(st1[4*rg],   st1[4*rg+1]);
            pk[1][2*rg+1] = pk2bf(st1[4*rg+2], st1[4*rg+3]);
        }
        union PF { bf16x8 vv; u32 w[4]; } pf[4];
#pragma unroll
        for (int ti2 = 0; ti2 < 2; ++ti2)
#pragma unroll
            for (int s = 0; s < 2; ++s) {
                u32x2 r0 = __builtin_amdgcn_permlane32_swap(pk[ti2][4*s],   pk[ti2][4*s+2], false, false);
                u32x2 r1 = __builtin_amdgcn_permlane32_swap(pk[ti2][4*s+1], pk[ti2][4*s+3], false, false);
                PF f;
                f.w[0] = r0[0]; f.w[1] = r1[0];
                f.w[2] = r0[1]; f.w[3] = r1[1];
                pf[ti2*2+s] = f;
            }
        // PV + row-sum (ones-MFMA on the matrix pipe)
#pragma unroll
        for (int ks = 0; ks < 4; ++ks) {
            acc0 = __builtin_amdgcn_mfma_f32_32x32x16_bf16(vr[ks],     pf[ks].vv, acc0, 0, 0, 0);
            acc1 = __builtin_amdgcn_mfma_f32_32x32x16_bf16(vr[4 + ks], pf[ks].vv, acc1, 0, 0, 0);
            accl = __builtin_amdgcn_mfma_f32_32x32x16_bf16(ones,       pf[ks].vv, accl, 0, 0, 0);
        }
    };

    // K and V double-buffered in regs: loads issued one full iteration ahead
    bf16x8 ka[8], kb2[8], va[8], vb2[8];
    int it = n_lo;
    if (it < n_hi) {
        loadK(ka, it << 6);
        loadV(va, it << 6);
        while (true) {
            if (it + 1 < n_hi) { loadK(kb2, (it + 1) << 6); loadV(vb2, (it + 1) << 6); }
            compute(ka, va, it << 6);
            ++it; if (it >= n_hi) break;
            if (it + 1 < n_hi) { loadK(ka, (it + 1) << 6); loadV(va, (it + 1) << 6); }
            compute(kb2, vb2, it << 6);
            ++it; if (it >= n_hi) break;
        }
    }

    // partial epilogue: unnormalized O (bf16) + row-sum l (f32)
    if (hl == 0) Ld[(size_t)bh * S + q0 + q5] = accl[0];
    size_t obase = ((size_t)(b * S + qglob)) * D + hd * DK;
#pragma unroll
    for (int rg = 0; rg < 4; ++rg) {
        uint2 wd;
        wd.x = pk2bf(acc0[4*rg],   acc0[4*rg+1]);
        wd.y = pk2bf(acc0[4*rg+2], acc0[4*rg+3]);
        *reinterpret_cast<uint2*>(Pd + obase + rg * 8 + hl * 4) = wd;
        uint2 we;
        we.x = pk2bf(acc1[4*rg],   acc1[4*rg+1]);
        we.y = pk2bf(acc1[4*rg+2], acc1[4*rg+3]);
        *reinterpret_cast<uint2*>(Pd + obase + 32 + rg * 8 + hl * 4) = we;
    }
}

// ---- merge partials: out = (P0+P1) / (l0+l1), written over P0 (read by out_gemm)
__global__ LB void merge_o(unsigned short* __restrict__ p0,
                           const unsigned short* __restrict__ p1,
                           const float* __restrict__ l0,
                           const float* __restrict__ l1) {
    size_t i = ((size_t)blockIdx.x * 256 + threadIdx.x) * 8;   // 8 elems/thread
    int row = (int)(i >> 10);            // token row 0..4095
    int col = (int)(i & 1023);
    int h = col >> 6;
    int b = row >> 11, s = row & (S - 1);
    size_t bh = (size_t)(b * H + h);
    float inv = 1.0f / (l0[bh * S + s] + l1[bh * S + s]);
    ushort4 a0 = *reinterpret_cast<const ushort4*>(p0 + i);
    ushort4 a1 = *reinterpret_cast<const ushort4*>(p0 + i + 4);
    ushort4 b0 = *reinterpret_cast<const ushort4*>(p1 + i);
    ushort4 b1 = *reinterpret_cast<const ushort4*>(p1 + i + 4);
    ushort4 o0, o1;
    o0.x = f2bf((bf2f(a0.x) + bf2f(b0.x)) * inv);
    o0.y = f2bf((bf2f(a0.y) + bf2f(b0.y)) * inv);
    o0.z = f2bf((bf2f(a0.z) + bf2f(b0.z)) * inv);
    o0.w = f2bf((bf2f(a0.w) + bf2f(b0.w)) * inv);
    o1.x = f2bf((bf2f(a1.x) + bf2f(b1.x)) * inv);
    o1.y = f2bf((bf2f(a1.y) + bf2f(b1.y)) * inv);
    o1.z = f2bf((bf2f(a1.z) + bf2f(b1.z)) * inv);
    o1.w = f2bf((bf2f(a1.w) + bf2f(b1.w)) * inv);
    *reinterpret_cast<ushort4*>(p0 + i)     = o0;
    *reinterpret_cast<ushort4*>(p0 + i + 4) = o1;
}

extern "C" void kernel_launch(void* const* d_in, const int* in_sizes, int n_in,
                              void* d_out, int out_size, void* d_ws, size_t ws_size,
                              hipStream_t stream) {
    const float* x  = (const float*)d_in[0];
    const float* wq = (const float*)d_in[1];
    const float* wk = (const float*)d_in[2];
    const float* wv = (const float*)d_in[3];
    const float* wo = (const float*)d_in[4];
    char* ws = (char*)d_ws;
    unsigned short* xb  = (unsigned short*)(ws);
    unsigned short* wqb = (unsigned short*)(ws + (size_t)(8  << 20));
    unsigned short* wkb = (unsigned short*)(ws + (size_t)(10 << 20));
    unsigned short* wvb = (unsigned short*)(ws + (size_t)(12 << 20));
    unsigned short* wob = (unsigned short*)(ws + (size_t)(14 << 20));
    unsigned short* qb  = (unsigned short*)(ws + (size_t)(16 << 20));
    unsigned short* kb  = (unsigned short*)(ws + (size_t)(24 << 20));
    unsigned short* vtb = (unsigned short*)(ws + (size_t)(32 << 20));
    unsigned short* p0  = (unsigned short*)(ws + (size_t)(40 << 20));  // merged -> out_gemm A
    unsigned short* p1  = (unsigned short*)(ws);                       // reuses xb (dead after gemm_qkv)
    float* l0 = (float*)(ws + (size_t)(8 << 20));                      // reuses wqb (dead after gemm_qkv)
    float* l1 = (float*)(ws + (size_t)(9 << 20));

    cvt_all<<<8192, 256, 0, stream>>>(x, wq, wk, wv, wo, xb);

    gemm_qkv<<<dim3(256, 3), 256, 0, stream>>>(xb, wqb, wkb, wvb, qb, kb, vtb);
    flash_attn<<<4096, 64, 0, stream>>>(qb, kb, vtb, p0, p1, l0, l1);
    merge_o<<<2048, 256, 0, stream>>>(p0, p1, l0, l1);
    out_gemm<<<512, 256, 0, stream>>>(p0, wob, (float*)d_out);
}

// Round 18
// 104.315 us; speedup vs baseline: 1.1510x; 1.1510x over previous
//
#include <hip/hip_runtime.h>

#define LB __launch_bounds__(256)

typedef __bf16 bf16x8 __attribute__((ext_vector_type(8)));
typedef float f32x4 __attribute__((ext_vector_type(4)));
typedef float f32x16 __attribute__((ext_vector_type(16)));
typedef unsigned int u32;
typedef unsigned int u32x2 __attribute__((ext_vector_type(2)));

constexpr int B = 2, S = 2048, D = 1024, H = 16, DK = 64;
constexpr int M = B * S;   // 4096 tokens
constexpr int K = D;       // 1024 inner dim for projections

__device__ __forceinline__ unsigned short f2bf(float f) {
    union { float f; unsigned u; } v; v.f = f;
    unsigned r = v.u + 0x7fffu + ((v.u >> 16) & 1u);
    return (unsigned short)(r >> 16);
}

__device__ __forceinline__ u32 pk2bf(float lo, float hi) {
    union { __bf16 h[2]; u32 w; } u;
    u.h[0] = (__bf16)lo; u.h[1] = (__bf16)hi;
    return u.w;
}

// bare v_exp_f32: exact for in-range scores; -1e30 -> 0. Skips the libm
// range-guard sequence (~5 instr/call, 32 calls/iter in flash).
__device__ __forceinline__ float fexp2(float x) {
    float y;
    asm("v_exp_f32 %0, %1" : "=v"(y) : "v"(x));
    return y;
}

__device__ __forceinline__ void gld_lds16(const unsigned short* g, unsigned short* l) {
    __builtin_amdgcn_global_load_lds(
        (const __attribute__((address_space(1))) unsigned int*)g,
        (__attribute__((address_space(3))) unsigned int*)l, 16, 0, 0);
}

// ---- fused fp32 -> bf16 convert of x|wq|wk|wv|wo into contiguous ws ----
__global__ LB void cvt_all(const float* __restrict__ x,  const float* __restrict__ wq,
                           const float* __restrict__ wk, const float* __restrict__ wv,
                           const float* __restrict__ wo, unsigned short* __restrict__ dst) {
    const size_t NX = (size_t)M * D;          // 4M
    const size_t NW = (size_t)D * D;          // 1M
    size_t i = ((size_t)blockIdx.x * 256 + threadIdx.x) * 4;
    if (i >= NX + 4 * NW) return;
    const float* src; size_t off;
    if      (i < NX)          { src = x;  off = i; }
    else if (i < NX + NW)     { src = wq; off = i - NX; }
    else if (i < NX + 2 * NW) { src = wk; off = i - NX - NW; }
    else if (i < NX + 3 * NW) { src = wv; off = i - NX - 2 * NW; }
    else                      { src = wo; off = i - NX - 3 * NW; }
    float4 f = *reinterpret_cast<const float4*>(src + off);
    ushort4 o;
    o.x = f2bf(f.x); o.y = f2bf(f.y); o.z = f2bf(f.z); o.w = f2bf(f.w);
    *reinterpret_cast<ushort4*>(dst + i) = o;
}

// ---- fused QKV projection (R15/R16-verified: scatter epilogue + XCD swizzle) ----
__global__ LB void gemm_qkv(const unsigned short* __restrict__ A,
                            const unsigned short* __restrict__ wqb,
                            const unsigned short* __restrict__ wkb,
                            const unsigned short* __restrict__ wvb,
                            unsigned short* __restrict__ qo,
                            unsigned short* __restrict__ ko,
                            unsigned short* __restrict__ vo) {
    __shared__ __align__(16) unsigned short lA[128 * 32];
    __shared__ __align__(16) unsigned short lB[128 * 32];
    const int z = blockIdx.y;
    const unsigned short* W = (z == 0) ? wqb : ((z == 1) ? wkb : wvb);
    int bid = blockIdx.x;
    int m0 = (((bid >> 6) << 3) | (bid & 7)) * 128;   // XCD-grouped m-tile
    int n0 = ((bid >> 3) & 7) * 128;
    int t = threadIdx.x;
    int w = t >> 6, lane = t & 63;
    int r = lane & 15, g = lane >> 4;
    int wr = w >> 1, wc = w & 1;
    int rowT = t >> 2, colOff = (t & 3) * 8;

    f32x4 acc[4][4];
#pragma unroll
    for (int mi = 0; mi < 4; ++mi)
#pragma unroll
        for (int ni = 0; ni < 4; ++ni) acc[mi][ni] = f32x4{0.f, 0.f, 0.f, 0.f};

    for (int k0 = 0; k0 < K; k0 += 32) {
        gld_lds16(A + (size_t)(m0 + rowT) * K + k0 + colOff,      lA + (w * 64) * 8);
        gld_lds16(A + (size_t)(m0 + 64 + rowT) * K + k0 + colOff, lA + (256 + w * 64) * 8);
        gld_lds16(W + (size_t)(n0 + rowT) * K + k0 + colOff,      lB + (w * 64) * 8);
        gld_lds16(W + (size_t)(n0 + 64 + rowT) * K + k0 + colOff, lB + (256 + w * 64) * 8);
        __syncthreads();
        bf16x8 af[4], bfr[4];
#pragma unroll
        for (int mi = 0; mi < 4; ++mi)
            af[mi] = *reinterpret_cast<const bf16x8*>(&lA[(wr * 64 + mi * 16 + r) * 32 + g * 8]);
#pragma unroll
        for (int ni = 0; ni < 4; ++ni)
            bfr[ni] = *reinterpret_cast<const bf16x8*>(&lB[(wc * 64 + ni * 16 + r) * 32 + g * 8]);
#pragma unroll
        for (int mi = 0; mi < 4; ++mi)
#pragma unroll
            for (int ni = 0; ni < 4; ++ni)
                acc[mi][ni] = __builtin_amdgcn_mfma_f32_16x16x32_bf16(af[mi], bfr[ni], acc[mi][ni], 0, 0, 0);
        __syncthreads();
    }

    const float QSCALE = 0.125f * 1.44269504088896341f;
    float scale = (z == 0) ? QSCALE : 1.0f;
    unsigned short* dst = (z == 0) ? qo : ((z == 1) ? ko : vo);
#pragma unroll
    for (int mi = 0; mi < 4; ++mi)
#pragma unroll
        for (int ni = 0; ni < 4; ++ni)
#pragma unroll
            for (int j = 0; j < 4; ++j) {
                int row = m0 + wr * 64 + mi * 16 + g * 4 + j;
                int col = n0 + wc * 64 + ni * 16 + r;
                int b = row >> 11, s = row & (S - 1);
                int h = col >> 6, dk = col & 63;
                size_t bh = (size_t)(b * H + h);
                unsigned short val = f2bf(acc[mi][ni][j] * scale);
                if (z == 0) {
                    dst[(bh * S + s) * DK + dk] = val;
                } else if (z == 1) {
                    int kt32 = s >> 5, q5k = s & 31;
                    int dsi = dk >> 4, hlk = (dk >> 3) & 1, e = dk & 7;
                    dst[(((bh * 64 + kt32) * 4 + dsi) * 64 + (hlk * 32 + q5k)) * 8 + e] = val;
                } else {
                    int ktile = s >> 6, ks2 = (s >> 4) & 3, hlv = (s >> 3) & 1, e = s & 7;
                    int rh = dk >> 5, q5r = dk & 31;
                    dst[(((bh * 32 + ktile) * 8 + rh * 4 + ks2) * 64 + (hlv * 32 + q5r)) * 8 + e] = val;
                }
            }
}

// ---- output projection: 128x64 tiles, 512 blocks (2 blocks/CU), XCD-grouped ----
__global__ LB void out_gemm(const unsigned short* __restrict__ A,
                            const unsigned short* __restrict__ W,
                            float* __restrict__ out) {
    __shared__ __align__(16) unsigned short lA[128 * 32];
    __shared__ __align__(16) unsigned short lB[64 * 32];
    int bid = blockIdx.x;                              // 512
    int m0 = (((bid >> 7) << 3) | (bid & 7)) * 128;    // m-tile 0..31, XCD-grouped
    int n0 = ((bid >> 3) & 15) * 64;                   // n-tile 0..15
    int t = threadIdx.x;
    int w = t >> 6, lane = t & 63;
    int r = lane & 15, g = lane >> 4;
    int wr = w >> 1, wc = w & 1;                       // 2m x 2n waves; wave = 64x32
    int rowT = t >> 2, colOff = (t & 3) * 8;

    f32x4 acc[4][2];
#pragma unroll
    for (int mi = 0; mi < 4; ++mi)
#pragma unroll
        for (int ni = 0; ni < 2; ++ni) acc[mi][ni] = f32x4{0.f, 0.f, 0.f, 0.f};

    for (int k0 = 0; k0 < K; k0 += 32) {
        gld_lds16(A + (size_t)(m0 + rowT) * K + k0 + colOff,      lA + (w * 64) * 8);
        gld_lds16(A + (size_t)(m0 + 64 + rowT) * K + k0 + colOff, lA + (256 + w * 64) * 8);
        gld_lds16(W + (size_t)(n0 + rowT) * K + k0 + colOff,      lB + (w * 64) * 8);
        __syncthreads();
        bf16x8 af[4], bfr[2];
#pragma unroll
        for (int mi = 0; mi < 4; ++mi)
            af[mi] = *reinterpret_cast<const bf16x8*>(&lA[(wr * 64 + mi * 16 + r) * 32 + g * 8]);
#pragma unroll
        for (int ni = 0; ni < 2; ++ni)
            bfr[ni] = *reinterpret_cast<const bf16x8*>(&lB[(wc * 32 + ni * 16 + r) * 32 + g * 8]);
#pragma unroll
        for (int mi = 0; mi < 4; ++mi)
#pragma unroll
            for (int ni = 0; ni < 2; ++ni)
                acc[mi][ni] = __builtin_amdgcn_mfma_f32_16x16x32_bf16(af[mi], bfr[ni], acc[mi][ni], 0, 0, 0);
        __syncthreads();
    }

#pragma unroll
    for (int mi = 0; mi < 4; ++mi)
#pragma unroll
        for (int ni = 0; ni < 2; ++ni)
#pragma unroll
            for (int j = 0; j < 4; ++j) {
                int row = m0 + wr * 64 + mi * 16 + g * 4 + j;
                int col = n0 + wc * 32 + ni * 16 + r;
                out[(size_t)row * D + col] = acc[mi][ni][j];
            }
}

// ---- causal flash attention: R16-verified structure; bare-v_exp_f32 softmax.
__global__ __launch_bounds__(64) void flash_attn(
        const unsigned short* __restrict__ q,
        const unsigned short* __restrict__ kmat,
        const unsigned short* __restrict__ vt,
        unsigned short* __restrict__ ao) {
    int bid = blockIdx.x;                 // 2048
    int kk = bid >> 8, cc = bid & 255;
    int r9 = (kk << 8) | ((kk & 1) ? (255 - cc) : cc);
    int qt = 63 - (r9 >> 5);              // serpentine: per-CU iter sum constant
    int bh = r9 & 31;
    int b = bh >> 4, hd = bh & 15;
    int q0 = qt << 5;
    int nt = (qt + 2) >> 1;               // kv-tiles of 64

    int l = threadIdx.x;
    int q5 = l & 31, hl = l >> 5;
    int qglob = q0 + q5;

    const unsigned short* qp = q    + (size_t)bh * S * DK;
    const unsigned short* kf = kmat + (size_t)bh * S * DK;   // fragment-major
    const unsigned short* vf = vt   + (size_t)bh * S * DK;   // fragment-major

    bf16x8 ones;
#pragma unroll
    for (int i = 0; i < 8; ++i) ones[i] = (__bf16)1.0f;

    const f32x16 z16 = {0,0,0,0,0,0,0,0,0,0,0,0,0,0,0,0};

    bf16x8 qf[4];
#pragma unroll
    for (int dsi = 0; dsi < 4; ++dsi)
        qf[dsi] = *reinterpret_cast<const bf16x8*>(qp + (size_t)qglob * DK + dsi * 16 + hl * 8);

    f32x16 acc0 = z16, acc1 = z16, accl = z16;

    // coalesced: each load is base + l*16B (1KB per wave-instruction)
    auto loadK = [&](bf16x8 (&kr)[8], int kb) {
        const unsigned short* base = kf + (size_t)(kb >> 5) * 4 * 512 + l * 8;
#pragma unroll
        for (int dsi = 0; dsi < 4; ++dsi) {
            kr[dsi]     = *reinterpret_cast<const bf16x8*>(base + dsi * 512);
            kr[4 + dsi] = *reinterpret_cast<const bf16x8*>(base + (4 + dsi) * 512);
        }
    };
    auto loadV = [&](bf16x8 (&vr)[8], int kb) {
        const unsigned short* base = vf + (size_t)(kb >> 6) * 8 * 512 + l * 8;
#pragma unroll
        for (int i2 = 0; i2 < 8; ++i2)
            vr[i2] = *reinterpret_cast<const bf16x8*>(base + i2 * 512);
    };
    auto compute = [&](bf16x8 (&kr)[8], bf16x8 (&vr)[8], int kb) {
        // st-init via C operand: no zero-copy
        f32x16 st0 = __builtin_amdgcn_mfma_f32_32x32x16_bf16(kr[0], qf[0], z16, 0, 0, 0);
        f32x16 st1 = __builtin_amdgcn_mfma_f32_32x32x16_bf16(kr[4], qf[0], z16, 0, 0, 0);
#pragma unroll
        for (int dsi = 1; dsi < 4; ++dsi) {
            st0 = __builtin_amdgcn_mfma_f32_32x32x16_bf16(kr[dsi],     qf[dsi], st0, 0, 0, 0);
            st1 = __builtin_amdgcn_mfma_f32_32x32x16_bf16(kr[4 + dsi], qf[dsi], st1, 0, 0, 0);
        }
        if (kb + 31 > q0) {
#pragma unroll
            for (int r = 0; r < 16; ++r) {
                int kv = kb + (r & 3) + 8 * (r >> 2) + 4 * hl;
                st0[r] = (kv <= qglob) ? st0[r] : -1e30f;
            }
        }
        if (kb + 63 > q0) {
#pragma unroll
            for (int r = 0; r < 16; ++r) {
                int kv = kb + 32 + (r & 3) + 8 * (r >> 2) + 4 * hl;
                st1[r] = (kv <= qglob) ? st1[r] : -1e30f;
            }
        }
        // static softmax: p = exp2(s) via bare v_exp_f32; masked -> 0
#pragma unroll
        for (int r = 0; r < 16; ++r) { st0[r] = fexp2(st0[r]); st1[r] = fexp2(st1[r]); }
        // pack to bf16; PF build via permlane32_swap builtin (R16-verified)
        u32 pk[2][8];
#pragma unroll
        for (int rg = 0; rg < 4; ++rg) {
            pk[0][2*rg]   = pk2bf(st0[4*rg],   st0[4*rg+1]);
            pk[0][2*rg+1] = pk2bf(st0[4*rg+2], st0[4*rg+3]);
            pk[1][2*rg]   = pk2bf(st1[4*rg],   st1[4*rg+1]);
            pk[1][2*rg+1] = pk2bf(st1[4*rg+2], st1[4*rg+3]);
        }
        union PF { bf16x8 vv; u32 w[4]; } pf[4];
#pragma unroll
        for (int ti2 = 0; ti2 < 2; ++ti2)
#pragma unroll
            for (int s = 0; s < 2; ++s) {
                u32x2 r0 = __builtin_amdgcn_permlane32_swap(pk[ti2][4*s],   pk[ti2][4*s+2], false, false);
                u32x2 r1 = __builtin_amdgcn_permlane32_swap(pk[ti2][4*s+1], pk[ti2][4*s+3], false, false);
                PF f;
                f.w[0] = r0[0]; f.w[1] = r1[0];
                f.w[2] = r0[1]; f.w[3] = r1[1];
                pf[ti2*2+s] = f;
            }
        // PV + row-sum (ones-MFMA on the matrix pipe)
#pragma unroll
        for (int ks = 0; ks < 4; ++ks) {
            acc0 = __builtin_amdgcn_mfma_f32_32x32x16_bf16(vr[ks],     pf[ks].vv, acc0, 0, 0, 0);
            acc1 = __builtin_amdgcn_mfma_f32_32x32x16_bf16(vr[4 + ks], pf[ks].vv, acc1, 0, 0, 0);
            accl = __builtin_amdgcn_mfma_f32_32x32x16_bf16(ones,       pf[ks].vv, accl, 0, 0, 0);
        }
    };

    // K and V double-buffered in regs: loads issued one full iteration ahead
    bf16x8 ka[8], kb2[8], va[8], vb2[8];
    loadK(ka, 0);
    loadV(va, 0);
    int it = 0;
    while (true) {
        if (it + 1 < nt) { loadK(kb2, (it + 1) << 6); loadV(vb2, (it + 1) << 6); }
        compute(ka, va, it << 6);
        ++it; if (it >= nt) break;
        if (it + 1 < nt) { loadK(ka, (it + 1) << 6); loadV(va, (it + 1) << 6); }
        compute(kb2, vb2, it << 6);
        ++it; if (it >= nt) break;
    }

    float inv = 1.0f / accl[0];
    size_t obase = ((size_t)(b * S + qglob)) * D + hd * DK;
#pragma unroll
    for (int rg = 0; rg < 4; ++rg) {
        uint2 wd;
        wd.x = pk2bf(acc0[4*rg]   * inv, acc0[4*rg+1] * inv);
        wd.y = pk2bf(acc0[4*rg+2] * inv, acc0[4*rg+3] * inv);
        *reinterpret_cast<uint2*>(ao + obase + rg * 8 + hl * 4) = wd;
        uint2 we;
        we.x = pk2bf(acc1[4*rg]   * inv, acc1[4*rg+1] * inv);
        we.y = pk2bf(acc1[4*rg+2] * inv, acc1[4*rg+3] * inv);
        *reinterpret_cast<uint2*>(ao + obase + 32 + rg * 8 + hl * 4) = we;
    }
}

extern "C" void kernel_launch(void* const* d_in, const int* in_sizes, int n_in,
                              void* d_out, int out_size, void* d_ws, size_t ws_size,
                              hipStream_t stream) {
    const float* x  = (const float*)d_in[0];
    const float* wq = (const float*)d_in[1];
    const float* wk = (const float*)d_in[2];
    const float* wv = (const float*)d_in[3];
    const float* wo = (const float*)d_in[4];
    char* ws = (char*)d_ws;
    unsigned short* xb  = (unsigned short*)(ws);
    unsigned short* wqb = (unsigned short*)(ws + (size_t)(8  << 20));
    unsigned short* wkb = (unsigned short*)(ws + (size_t)(10 << 20));
    unsigned short* wvb = (unsigned short*)(ws + (size_t)(12 << 20));
    unsigned short* wob = (unsigned short*)(ws + (size_t)(14 << 20));
    unsigned short* qb  = (unsigned short*)(ws + (size_t)(16 << 20));
    unsigned short* kb  = (unsigned short*)(ws + (size_t)(24 << 20));
    unsigned short* vtb = (unsigned short*)(ws + (size_t)(32 << 20));
    unsigned short* aob = (unsigned short*)(ws + (size_t)(40 << 20));

    cvt_all<<<8192, 256, 0, stream>>>(x, wq, wk, wv, wo, xb);

    gemm_qkv<<<dim3(256, 3), 256, 0, stream>>>(xb, wqb, wkb, wvb, qb, kb, vtb);
    flash_attn<<<2048, 64, 0, stream>>>(qb, kb, vtb, aob);
    out_gemm<<<512, 256, 0, stream>>>(aob, wob, (float*)d_out);
}